// Round 1
// baseline (1220.071 us; speedup 1.0000x reference)
//
#include <hip/hip_runtime.h>
#include <math.h>

#define S_ 2048
#define N_ 256
#define MID_ 512
#define NB_ 8
#define JSL_ 64   // MID_/NB_
#define LN_EPS_ 1e-5f

__device__ __forceinline__ float gelu_exact(float x){
    return 0.5f * x * (1.0f + erff(x * 0.70710678118654752440f));
}

// ---------------- setup kernels ----------------

__global__ void k_init(const float* __restrict__ xs, const float* __restrict__ gamma,
                       const float* __restrict__ w2,
                       float* __restrict__ probs, float* __restrict__ w2T,
                       float* __restrict__ gw2, unsigned int* __restrict__ wmask32,
                       int* __restrict__ flags)
{
    int idx = blockIdx.x * blockDim.x + threadIdx.x;   // grid covers 524288
    if (idx < S_*N_) probs[idx] = xs[idx];
    if (idx < MID_*N_) {
        int j = idx / N_, c = idx % N_;
        float v = w2[idx];
        gw2[idx] = gamma[j] * v;
        w2T[c*MID_ + j] = v;
    }
    if (idx < (N_*N_)/4) wmask32[idx] = 0u;
    if (idx < NB_) flags[idx] = 0;
}

__global__ void k_mask(const int* __restrict__ ids, unsigned char* __restrict__ wmask){
    int i = blockIdx.x*blockDim.x + threadIdx.x;       // 524288 = S_*N_
    if (i < S_*N_){
        int t = i & (N_-1);        // i = k*256 + t  (row-major ids_ary[k][t])
        int c = ids[i];
        wmask[t*N_ + c] = 1;       // benign write race, value always 1
    }
}

__global__ void k_ab(const float* __restrict__ gamma, const float* __restrict__ beta,
                     const float* __restrict__ w2, const float* __restrict__ b2,
                     float* __restrict__ A, float* __restrict__ Bc){
    __shared__ float ra[256], rb[256];
    int c = blockIdx.x, tid = threadIdx.x;
    float a = 0.f, b = 0.f;
    for (int j = tid; j < MID_; j += 256){
        float v = w2[j*N_ + c];
        a += gamma[j]*v;
        b += beta[j]*v;
    }
    ra[tid] = a; rb[tid] = b; __syncthreads();
    for (int off = 128; off > 0; off >>= 1){
        if (tid < off){ ra[tid] += ra[tid+off]; rb[tid] += rb[tid+off]; }
        __syncthreads();
    }
    if (tid == 0){ A[c] = ra[0]; Bc[c] = rb[0] + b2[c]; }
}

// ---------------- exact full-row step (t = 0..2) ----------------

__global__ __launch_bounds__(256) void k_full_rows(
    const float* __restrict__ probs, const float* __restrict__ w1,
    const float* __restrict__ b1, const float* __restrict__ gamma,
    const float* __restrict__ beta, const float* __restrict__ w2T,
    const float* __restrict__ b2, const int* __restrict__ ids,
    float* __restrict__ ps, int t)
{
    __shared__ float prow[8][N_];
    int tid = threadIdx.x;
    int r0 = blockIdx.x * 8;
    for (int i = tid; i < 8*N_; i += 256)
        prow[i>>8][i&255] = probs[(r0 + (i>>8))*N_ + (i&255)];
    __syncthreads();
    int r = tid >> 5, jg = tid & 31;      // 8 rows x 32 threads; 2 rows per wave
    float h[16];
    #pragma unroll
    for (int m = 0; m < 16; m++) h[m] = b1[jg + 32*m];
    for (int c = 0; c < N_; c++){
        float p = prow[r][c];
        const float* w1r = w1 + c*MID_;
        #pragma unroll
        for (int m = 0; m < 16; m++) h[m] = fmaf(p, w1r[jg + 32*m], h[m]);
    }
    float s1 = 0.f, s2 = 0.f;
    #pragma unroll
    for (int m = 0; m < 16; m++){
        float g = gelu_exact(h[m]);
        h[m] = g; s1 += g; s2 += g*g;
    }
    #pragma unroll
    for (int off = 16; off > 0; off >>= 1){
        s1 += __shfl_xor(s1, off, 32);
        s2 += __shfl_xor(s2, off, 32);
    }
    float mu  = s1 * (1.f/MID_);
    float var = s2 * (1.f/MID_) - mu*mu;
    float inv = rsqrtf(var + LN_EPS_);
    int rg = r0 + r;
    int id = ids[rg*N_ + t];
    const float* wrow = w2T + id*MID_;
    float acc = 0.f;
    #pragma unroll
    for (int m = 0; m < 16; m++){
        int j = jg + 32*m;
        float hn = (h[m] - mu)*inv*gamma[j] + beta[j];
        acc = fmaf(hn, wrow[j], acc);
    }
    #pragma unroll
    for (int off = 16; off > 0; off >>= 1) acc += __shfl_xor(acc, off, 32);
    if (jg == 0) ps[rg] = 1.f/(1.f + expf(-(acc + b2[id])));
}

// last-k-wins scatter (numpy fancy-assignment semantics)
__global__ void k_scatter(const int* __restrict__ ids, const float* __restrict__ ps,
                          float* __restrict__ newval, int* __restrict__ wrote, int t){
    __shared__ int lastk[N_];
    int tid = threadIdx.x;
    lastk[tid] = -1;
    __syncthreads();
    for (int k = tid; k < S_; k += 256) atomicMax(&lastk[ids[k*N_ + t]], k);
    __syncthreads();
    int lk = lastk[tid];
    wrote[tid] = (lk >= 0) ? 1 : 0;
    if (lk >= 0) newval[tid] = ps[lk];
}

__global__ void k_apply(float* __restrict__ probs, const float* __restrict__ newval,
                        const int* __restrict__ wrote){
    int idx = blockIdx.x*blockDim.x + threadIdx.x;     // 524288
    int c = idx & (N_-1);
    if (wrote[c]) probs[idx] = newval[c];
}

// ---------------- persistent single-row fast path (t = 3..255) ----------------
// 8 blocks; block b owns MID-slice [b*64, b*64+64). One cross-block exchange
// per step: P1[c] = sum_j g_j * (gamma_j * w2[j,c]) plus (sum g, sum g^2).
// s[c] = inv*(P1sum[c] - mu*A[c]) + B[c];  LN folded through the matvec.

__global__ __launch_bounds__(512) void k_fast(
    const float* __restrict__ w1, const float* __restrict__ b1,
    const float* __restrict__ gw2, const float* __restrict__ A,
    const float* __restrict__ Bc, const unsigned char* __restrict__ wmask,
    const float* __restrict__ probs, float* __restrict__ partials,
    int* __restrict__ flags, float* __restrict__ commonFinal, int t0)
{
    __shared__ float w1s[N_*JSL_];     // [c][jj], 64 KiB
    __shared__ float gw2s[JSL_*N_];    // [jj][c], 64 KiB
    __shared__ float common[N_];
    __shared__ float hpart[8][JSL_];
    __shared__ float gvals[JSL_];
    __shared__ float pr[NB_][2];
    __shared__ float gstats[2];

    int tid = threadIdx.x, b = blockIdx.x;
    int j0 = b * JSL_;
    for (int i = tid; i < N_*JSL_; i += 512){
        int c = i >> 6, jj = i & 63;
        w1s[i] = w1[c*MID_ + j0 + jj];
    }
    for (int i = tid; i < JSL_*N_; i += 512){
        int jj = i >> 8, c = i & 255;
        gw2s[i] = gw2[(j0 + jj)*N_ + c];
    }
    if (tid < N_) common[tid] = probs[tid];            // all rows identical by t0
    float Ac  = (tid < N_)   ? A[tid]      : 0.f;
    float Bcc = (tid < N_)   ? Bc[tid]     : 0.f;
    float b1v = (tid < JSL_) ? b1[j0+tid]  : 0.f;
    __syncthreads();

    for (int t = t0; t < N_; t++){
        int slot = t & 1;
        // stage 1: partial h for own j-slice (8 c-groups x 64 j)
        {
            int jj = tid & 63, cg = tid >> 6;
            float acc = 0.f;
            int cbase = cg * 32;
            #pragma unroll 8
            for (int cc = 0; cc < 32; cc++){
                float p = common[cbase + cc];
                acc = fmaf(p, w1s[(cbase + cc)*JSL_ + jj], acc);
            }
            hpart[cg][jj] = acc;
        }
        __syncthreads();
        if (tid < JSL_){
            float h = b1v;
            #pragma unroll
            for (int cg = 0; cg < 8; cg++) h += hpart[cg][tid];
            float g = gelu_exact(h);
            gvals[tid] = g;
            float s1 = g, s2 = g*g;
            #pragma unroll
            for (int off = 32; off > 0; off >>= 1){
                s1 += __shfl_xor(s1, off, 64);
                s2 += __shfl_xor(s2, off, 64);
            }
            if (tid == 0){ gstats[0] = s1; gstats[1] = s2; }
        }
        __syncthreads();
        // stage 2: P1[c] partial matvec for own slice
        if (tid < N_){
            float p1 = 0.f;
            #pragma unroll 8
            for (int jj = 0; jj < JSL_; jj++)
                p1 = fmaf(gvals[jj], gw2s[jj*N_ + tid], p1);
            partials[(slot*NB_ + b)*258 + tid] = p1;
        }
        if (tid == 0){
            partials[(slot*NB_ + b)*258 + 256] = gstats[0];
            partials[(slot*NB_ + b)*258 + 257] = gstats[1];
        }
        __syncthreads();
        if (tid == 0){
            __threadfence();
            __hip_atomic_store(&flags[b], t+1, __ATOMIC_RELEASE, __HIP_MEMORY_SCOPE_AGENT);
        }
        if (tid < NB_){
            while (__hip_atomic_load(&flags[tid], __ATOMIC_ACQUIRE,
                                     __HIP_MEMORY_SCOPE_AGENT) < t+1){}
            pr[tid][0] = partials[(slot*NB_ + tid)*258 + 256];
            pr[tid][1] = partials[(slot*NB_ + tid)*258 + 257];
        }
        __syncthreads();
        // stage 4: redundant per-block finish: stats, s[c], sigmoid, common update
        if (tid < N_){
            float s1 = 0.f;
            #pragma unroll
            for (int bb = 0; bb < NB_; bb++)
                s1 += partials[(slot*NB_ + bb)*258 + tid];
            float S1 = 0.f, S2 = 0.f;
            #pragma unroll
            for (int bb = 0; bb < NB_; bb++){ S1 += pr[bb][0]; S2 += pr[bb][1]; }
            float mu  = S1 * (1.f/MID_);
            float var = S2 * (1.f/MID_) - mu*mu;
            float inv = rsqrtf(var + LN_EPS_);
            float s = inv*(s1 - mu*Ac) + Bcc;
            float o = 1.f/(1.f + expf(-s));
            if (wmask[t*N_ + tid]) common[tid] = o;
        }
        __syncthreads();
    }
    if (b == 0 && tid < N_) commonFinal[tid] = common[tid];
}

__global__ void k_out(const float* __restrict__ commonFinal, float* __restrict__ out){
    int idx = blockIdx.x*blockDim.x + threadIdx.x;     // 524288
    out[idx] = commonFinal[idx & (N_-1)];
}

// ---------------- launch ----------------

extern "C" void kernel_launch(void* const* d_in, const int* in_sizes, int n_in,
                              void* d_out, int out_size, void* d_ws, size_t ws_size,
                              hipStream_t stream)
{
    const float* xs    = (const float*)d_in[0];
    const int*   ids   = (const int*)  d_in[1];
    const float* w1    = (const float*)d_in[2];
    const float* b1    = (const float*)d_in[3];
    const float* gamma = (const float*)d_in[4];
    const float* beta  = (const float*)d_in[5];
    const float* w2    = (const float*)d_in[6];
    const float* b2    = (const float*)d_in[7];
    float* out = (float*)d_out;

    float* ws      = (float*)d_ws;
    float* probs   = ws;                     // 524288 f32
    float* w2T     = probs + S_*N_;          // 131072
    float* gw2     = w2T + N_*MID_;          // 131072
    float* A       = gw2 + MID_*N_;          // 256
    float* Bc      = A + N_;                 // 256
    float* ps      = Bc + N_;                // 2048
    float* newval  = ps + S_;                // 256
    int*   wrote   = (int*)(newval + N_);    // 256
    unsigned char* wmask = (unsigned char*)(wrote + N_);  // 65536 B
    float* partials = (float*)(wmask + N_*N_);            // 2*NB_*258 f32
    int*   flags    = (int*)(partials + 2*NB_*258);       // NB_
    float* commonFinal = (float*)(flags + 16);            // 256

    k_init<<<2048, 256, 0, stream>>>(xs, gamma, w2, probs, w2T, gw2,
                                     (unsigned int*)wmask, flags);
    k_mask<<<2048, 256, 0, stream>>>(ids, wmask);
    k_ab<<<256, 256, 0, stream>>>(gamma, beta, w2, b2, A, Bc);

    for (int t = 0; t < 3; t++){
        k_full_rows<<<256, 256, 0, stream>>>(probs, w1, b1, gamma, beta, w2T, b2,
                                             ids, ps, t);
        k_scatter<<<1, 256, 0, stream>>>(ids, ps, newval, wrote, t);
        k_apply<<<2048, 256, 0, stream>>>(probs, newval, wrote);
    }

    k_fast<<<NB_, 512, 0, stream>>>(w1, b1, gw2, A, Bc, wmask, probs,
                                    partials, flags, commonFinal, 3);
    k_out<<<2048, 256, 0, stream>>>(commonFinal, out);
}